// Round 4
// baseline (273.915 us; speedup 1.0000x reference)
//
#include <hip/hip_runtime.h>
#include <stdint.h>

#define BB 8
#define NN 2048
#define NC 80
#define MAXDET 512
#define WPR 32            // 64-bit words per row of the suppression matrix (2048/64)

// ---------------- ws layout (bytes) ----------------
// keysA  : uint64 [BB][NN]        @ 0        (131072)   unsorted keys
// keysB  : uint64 [BB][NN]        @ 131072   (131072)   sorted keys
// sboxes : float  [BB][NN][4]     @ 262144   (262144)
// kidx   : int32  [BB][MAXDET]    @ 524288   (16384)
// kcount : int32  [BB]            @ 540672   (128 pad)
// sup    : uint64 [BB][NN][WPR]   @ 544768   (4194304)
// total ~4.52 MB

#define ORD_HALF 0xBF000000u   // orderable(0.5f)

// Kernel 0: conf = 1/(1+expf(-max_logit)) computed step-by-step in f32
// (matches numpy/XLA f32 sigmoid rounding chain, hence its tie GROUPING).
// key = orderable(conf) << 32 | (N-1-n): descending conf, ties -> smaller n.
__global__ void k_conf(const float* __restrict__ cls, uint64_t* __restrict__ keys) {
    int gid = blockIdx.x * blockDim.x + threadIdx.x;      // 0 .. BB*NN-1
    const float4* p = (const float4*)(cls + (size_t)gid * NC);
    float m = -3.0e38f;
#pragma unroll
    for (int i = 0; i < NC / 4; ++i) {
        float4 v = p[i];
        m = fmaxf(m, fmaxf(fmaxf(v.x, v.y), fmaxf(v.z, v.w)));
    }
    float e  = expf(-m);                 // f32
    float cf = 1.0f / (1.0f + e);        // f32 step-by-step
    uint32_t u = __float_as_uint(cf);
    u = (u & 0x80000000u) ? ~u : (u | 0x80000000u);       // monotone float->uint map
    int n = gid & (NN - 1);
    keys[gid] = ((uint64_t)u << 32) | (uint32_t)(NN - 1 - n);
}

// Kernel 1: rank sort (bulletproof). rank = #{m : key[m] > key[n]}; keys are
// distinct (index embedded), so rank is an exact permutation. Descending order.
__global__ __launch_bounds__(1024) void k_rank(const uint64_t* __restrict__ keys_in,
                                               uint64_t* __restrict__ keys_out,
                                               const float* __restrict__ boxes,
                                               float* __restrict__ sboxes) {
    __shared__ uint64_t sk[NN];   // 16 KB
    int b = blockIdx.x, t = threadIdx.x;
    sk[t]        = keys_in[(size_t)b * NN + t];
    sk[t + 1024] = keys_in[(size_t)b * NN + t + 1024];
    __syncthreads();
    for (int e = t; e < NN; e += 1024) {
        uint64_t mykey = sk[e];
        int rank = 0;
        for (int mm = 0; mm < NN; ++mm) rank += (sk[mm] > mykey) ? 1 : 0;
        keys_out[(size_t)b * NN + rank] = mykey;
        int orig = (NN - 1) - (int)(mykey & 0xFFFFFFFFull);
        ((float4*)sboxes)[(size_t)b * NN + rank] =
            ((const float4*)boxes)[(size_t)b * NN + orig];
    }
}

// Kernel 2: suppression bit matrix (unchanged). Block = 64-row x 256-col tile.
// Bit c of word gw of row r: IoU(r, col) > 0.5 && col > r.
__global__ void k_sup(const float* __restrict__ sboxes, uint64_t* __restrict__ sup) {
#pragma clang fp contract(off)
    __shared__ float cy1[256], cx1[256], cy2[256], cx2[256], car[256];
    __shared__ float ry1[64], rx1[64], ry2[64], rx2[64], rar[64];
    int rt = blockIdx.x, ct = blockIdx.y, b = blockIdx.z;
    int t = threadIdx.x;
    int col0 = ct << 8, row0 = rt << 6;
    {
        float4 bx = ((const float4*)sboxes)[(size_t)b * NN + col0 + t];
        cy1[t] = bx.x; cx1[t] = bx.y; cy2[t] = bx.z; cx2[t] = bx.w;
        car[t] = (bx.z - bx.x) * (bx.w - bx.y);
        if (t < 64) {
            float4 rb = ((const float4*)sboxes)[(size_t)b * NN + row0 + t];
            ry1[t] = rb.x; rx1[t] = rb.y; ry2[t] = rb.z; rx2[t] = rb.w;
            rar[t] = (rb.z - rb.x) * (rb.w - rb.y);
        }
    }
    __syncthreads();
    int lr = t & 63, lg = t >> 6;
    int r = row0 + lr;
    int gw = (ct << 2) + lg;
    int cbase = gw << 6;
    uint64_t w = 0;
    if (cbase + 63 > r) {                  // tile not entirely at/below diagonal
        float y1 = ry1[lr], x1 = rx1[lr], y2 = ry2[lr], x2 = rx2[lr], ar = rar[lr];
        int lcb = lg << 6;
        for (int c = 0; c < 64; ++c) {
            int lc = lcb + c;
            float ih = fmaxf(fminf(y2, cy2[lc]) - fmaxf(y1, cy1[lc]), 0.0f);
            float iw = fmaxf(fminf(x2, cx2[lc]) - fmaxf(x1, cx1[lc]), 0.0f);
            float inter = ih * iw;
            float uni = (ar + car[lc]) - inter;
            float iou = inter / fmaxf(uni, 1e-9f);
            if ((iou > 0.5f) & ((cbase + c) > r)) w |= (1ull << c);
        }
    }
    sup[((size_t)b * NN + r) * WPR + gw] = w;
}

// Kernel 3: greedy scan, direct-global version. One 64-thread wave per batch.
// Lanes 0..31: lane l owns removed-word l (register kb). Invalid boxes are
// pre-marked removed (kb = ~vmask) — equivalent to keep_init = valid.
// Per 8-row chunk: prefetch next chunk's words (A = word l, G = word g
// broadcast); one shfl per 64-row group refreshes the local rw copy.
__global__ __launch_bounds__(64) void k_nms(const uint64_t* __restrict__ keys,
                                            const float* __restrict__ sboxes,
                                            const uint64_t* __restrict__ sup,
                                            int* __restrict__ kidx,
                                            int* __restrict__ kcount,
                                            float* __restrict__ out_box,
                                            float* __restrict__ out_conf) {
    __shared__ uint64_t kmaskS[WPR];
    __shared__ int pfx[WPR];
    __shared__ int s_kc;
    int b = blockIdx.x, t = threadIdx.x;       // 64 threads
    const uint64_t* supb = sup + (size_t)b * NN * WPR;
    const uint64_t* keyb = keys + (size_t)b * NN;

    if (t < 32) {
        const int l = t;
        uint64_t vm = 0;
        for (int c = 0; c < 64; ++c) {
            uint32_t hi = (uint32_t)(keyb[(l << 6) | c] >> 32);
            vm |= ((uint64_t)(hi > ORD_HALF)) << c;      // conf > 0.5f
        }
        uint64_t kb = ~vm;        // invalid = pre-removed
        uint64_t km = 0, rw = 0;
        uint64_t A[8], G[8], An[8], Gn[8];
#pragma unroll
        for (int j = 0; j < 8; ++j) { A[j] = supb[j * WPR + l]; G[j] = supb[j * WPR + 0]; }
        for (int ch = 0; ch < NN / 8; ++ch) {
            int base = ch * 8, g = base >> 6;
            if ((base & 63) == 0) rw = __shfl(kb, g);    // refresh group word
            if (ch + 1 < NN / 8) {
                int nb = base + 8, ng = nb >> 6;
#pragma unroll
                for (int j = 0; j < 8; ++j) {
                    An[j] = supb[(size_t)(nb + j) * WPR + l];
                    Gn[j] = supb[(size_t)(nb + j) * WPR + ng];
                }
            }
#pragma unroll
            for (int j = 0; j < 8; ++j) {
                int bi = (base + j) & 63;
                bool kept = ((rw >> bi) & 1ull) == 0;
                if (kept) {
                    rw |= G[j];                          // in-group suppression
                    kb |= A[j];                          // lane's word suppression
                    km |= ((uint64_t)(l == g)) << bi;    // record keep
                }
            }
#pragma unroll
            for (int j = 0; j < 8; ++j) { A[j] = An[j]; G[j] = Gn[j]; }
        }
        kmaskS[l] = km;
    }
    __syncthreads();
    if (t == 0) {
        int s = 0;
        for (int w2 = 0; w2 < WPR; ++w2) { pfx[w2] = s; s += __popcll(kmaskS[w2]); }
        s_kc = (s < MAXDET) ? s : MAXDET;
        kcount[b] = s_kc;
    }
    __syncthreads();
    for (int i = t; i < NN; i += 64) {
        uint64_t m = kmaskS[i >> 6];
        if ((m >> (i & 63)) & 1ull) {
            int rank = pfx[i >> 6] + __popcll(m & ((1ull << (i & 63)) - 1ull));
            if (rank < MAXDET) {
                ((float4*)out_box)[(size_t)b * MAXDET + rank] =
                    ((const float4*)sboxes)[(size_t)b * NN + i];
                uint64_t kk = keyb[i];
                uint32_t u = (uint32_t)(kk >> 32);
                float cf = (u & 0x80000000u) ? __uint_as_float(u ^ 0x80000000u)
                                             : __uint_as_float(~u);
                out_conf[(size_t)b * MAXDET + rank] = cf;
                kidx[b * MAXDET + rank] = (NN - 1) - (int)(kk & 0xFFFFFFFFull);
            }
        }
    }
    for (int k = s_kc + t; k < MAXDET; k += 64) {
        ((float4*)out_box)[(size_t)b * MAXDET + k] = make_float4(0.f, 0.f, 0.f, 0.f);
        out_conf[(size_t)b * MAXDET + k] = 0.0f;
    }
}

// Kernel 4: softmax gather for kept rows; zero-fill the rest. One wave per slot.
__global__ void k_softmax(const float* __restrict__ cls, const int* __restrict__ kidx,
                          const int* __restrict__ kcount, float* __restrict__ out_cls) {
    int k = blockIdx.x, b = blockIdx.y, lane = threadIdx.x;  // 64 threads
    float* dst = out_cls + ((size_t)b * MAXDET + k) * NC;
    if (k >= kcount[b]) {
        dst[lane] = 0.0f;
        if (lane < NC - 64) dst[64 + lane] = 0.0f;
        return;
    }
    int n = kidx[b * MAXDET + k];
    const float* src = cls + ((size_t)b * NN + n) * NC;
    float x0 = src[lane];
    float x1 = (lane < NC - 64) ? src[64 + lane] : -3.0e38f;
    float m = fmaxf(x0, x1);
    for (int o = 32; o > 0; o >>= 1) m = fmaxf(m, __shfl_xor(m, o));
    float e0 = expf(x0 - m);
    float e1 = (lane < NC - 64) ? expf(x1 - m) : 0.0f;
    float s = e0 + e1;
    for (int o = 32; o > 0; o >>= 1) s += __shfl_xor(s, o);
    dst[lane] = e0 / s;
    if (lane < NC - 64) dst[64 + lane] = e1 / s;
}

extern "C" void kernel_launch(void* const* d_in, const int* in_sizes, int n_in,
                              void* d_out, int out_size, void* d_ws, size_t ws_size,
                              hipStream_t stream) {
    const float* boxes = (const float*)d_in[0];   // [8][2048][4]
    const float* cls   = (const float*)d_in[1];   // [8][2048][80]
    float* out      = (float*)d_out;
    float* out_box  = out;                          // [8][512][4]
    float* out_cls  = out + BB * MAXDET * 4;        // [8][512][80]
    float* out_conf = out + BB * MAXDET * (4 + NC); // [8][512]

    char* ws = (char*)d_ws;
    uint64_t* keysA  = (uint64_t*)(ws + 0);
    uint64_t* keysB  = (uint64_t*)(ws + 131072);
    float*    sboxes = (float*)(ws + 262144);
    int*      kidx   = (int*)(ws + 524288);
    int*      kcount = (int*)(ws + 540672);
    uint64_t* sup    = (uint64_t*)(ws + 544768);

    k_conf<<<(BB * NN) / 256, 256, 0, stream>>>(cls, keysA);
    k_rank<<<BB, 1024, 0, stream>>>(keysA, keysB, boxes, sboxes);
    k_sup<<<dim3(NN / 64, NN / 256, BB), 256, 0, stream>>>(sboxes, sup);
    k_nms<<<BB, 64, 0, stream>>>(keysB, sboxes, sup, kidx, kcount, out_box, out_conf);
    k_softmax<<<dim3(MAXDET, BB), 64, 0, stream>>>(cls, kidx, kcount, out_cls);
}

// Round 5
// 156.917 us; speedup vs baseline: 1.7456x; 1.7456x over previous
//
#include <hip/hip_runtime.h>
#include <stdint.h>

#define BB 8
#define NN 2048
#define NC 80
#define MAXDET 512
#define WPR 32            // 64-bit words per row of the suppression matrix (2048/64)

// ---------------- ws layout (bytes) ----------------
// keysA  : uint64 [BB][NN]        @ 0        (131072)   unsorted keys
// keysB  : uint64 [BB][NN]        @ 131072   (131072)   sorted keys
// sboxes : float  [BB][NN][4]     @ 262144   (262144)
// kidx   : int32  [BB][MAXDET]    @ 524288   (16384)
// kcount : int32  [BB]            @ 540672   (128 pad)
// sup    : uint64 [BB][NN][WPR]   @ 544768   (4194304)
// total ~4.52 MB

#define ORD_HALF 0xBF000000u   // orderable(0.5f)

// Kernel 0: conf = 1/(1+expf(-max_logit)) computed step-by-step in f32
// (matches numpy/XLA f32 sigmoid rounding chain, hence its tie GROUPING).
// key = orderable(conf) << 32 | (N-1-n): descending conf, ties -> smaller n.
__global__ void k_conf(const float* __restrict__ cls, uint64_t* __restrict__ keys) {
    int gid = blockIdx.x * blockDim.x + threadIdx.x;      // 0 .. BB*NN-1
    const float4* p = (const float4*)(cls + (size_t)gid * NC);
    float m = -3.0e38f;
#pragma unroll
    for (int i = 0; i < NC / 4; ++i) {
        float4 v = p[i];
        m = fmaxf(m, fmaxf(fmaxf(v.x, v.y), fmaxf(v.z, v.w)));
    }
    float e  = expf(-m);                 // f32
    float cf = 1.0f / (1.0f + e);        // f32 step-by-step
    uint32_t u = __float_as_uint(cf);
    u = (u & 0x80000000u) ? ~u : (u | 0x80000000u);       // monotone float->uint map
    int n = gid & (NN - 1);
    keys[gid] = ((uint64_t)u << 32) | (uint32_t)(NN - 1 - n);
}

// Kernel 1: rank sort (bulletproof). rank = #{m : key[m] > key[n]}; keys are
// distinct (index embedded), so rank is an exact permutation. Descending order.
__global__ __launch_bounds__(1024) void k_rank(const uint64_t* __restrict__ keys_in,
                                               uint64_t* __restrict__ keys_out,
                                               const float* __restrict__ boxes,
                                               float* __restrict__ sboxes) {
    __shared__ uint64_t sk[NN];   // 16 KB
    int b = blockIdx.x, t = threadIdx.x;
    sk[t]        = keys_in[(size_t)b * NN + t];
    sk[t + 1024] = keys_in[(size_t)b * NN + t + 1024];
    __syncthreads();
    for (int e = t; e < NN; e += 1024) {
        uint64_t mykey = sk[e];
        int rank = 0;
        for (int mm = 0; mm < NN; ++mm) rank += (sk[mm] > mykey) ? 1 : 0;
        keys_out[(size_t)b * NN + rank] = mykey;
        int orig = (NN - 1) - (int)(mykey & 0xFFFFFFFFull);
        ((float4*)sboxes)[(size_t)b * NN + rank] =
            ((const float4*)boxes)[(size_t)b * NN + orig];
    }
}

// Kernel 2: suppression bit matrix (unchanged). Block = 64-row x 256-col tile.
// Bit c of word gw of row r: IoU(r, col) > 0.5 && col > r.
__global__ void k_sup(const float* __restrict__ sboxes, uint64_t* __restrict__ sup) {
#pragma clang fp contract(off)
    __shared__ float cy1[256], cx1[256], cy2[256], cx2[256], car[256];
    __shared__ float ry1[64], rx1[64], ry2[64], rx2[64], rar[64];
    int rt = blockIdx.x, ct = blockIdx.y, b = blockIdx.z;
    int t = threadIdx.x;
    int col0 = ct << 8, row0 = rt << 6;
    {
        float4 bx = ((const float4*)sboxes)[(size_t)b * NN + col0 + t];
        cy1[t] = bx.x; cx1[t] = bx.y; cy2[t] = bx.z; cx2[t] = bx.w;
        car[t] = (bx.z - bx.x) * (bx.w - bx.y);
        if (t < 64) {
            float4 rb = ((const float4*)sboxes)[(size_t)b * NN + row0 + t];
            ry1[t] = rb.x; rx1[t] = rb.y; ry2[t] = rb.z; rx2[t] = rb.w;
            rar[t] = (rb.z - rb.x) * (rb.w - rb.y);
        }
    }
    __syncthreads();
    int lr = t & 63, lg = t >> 6;
    int r = row0 + lr;
    int gw = (ct << 2) + lg;
    int cbase = gw << 6;
    uint64_t w = 0;
    if (cbase + 63 > r) {                  // tile not entirely at/below diagonal
        float y1 = ry1[lr], x1 = rx1[lr], y2 = ry2[lr], x2 = rx2[lr], ar = rar[lr];
        int lcb = lg << 6;
        for (int c = 0; c < 64; ++c) {
            int lc = lcb + c;
            float ih = fmaxf(fminf(y2, cy2[lc]) - fmaxf(y1, cy1[lc]), 0.0f);
            float iw = fmaxf(fminf(x2, cx2[lc]) - fmaxf(x1, cx1[lc]), 0.0f);
            float inter = ih * iw;
            float uni = (ar + car[lc]) - inter;
            float iou = inter / fmaxf(uni, 1e-9f);
            if ((iou > 0.5f) & ((cbase + c) > r)) w |= (1ull << c);
        }
    }
    sup[((size_t)b * NN + r) * WPR + gw] = w;
}

// Kernel 3: greedy scan, LDS-staged double-buffer + exact early exit.
// 256 threads: wave 0 lanes 0..31 scan group g from buf[g&1]; waves 1..3
// stage group g+1 (16 KB) into buf[(g+1)&1]. One barrier per group.
// Early exit: output only consumes the first MAXDET kept rows (top_k of a
// descending-sorted masked score vector), so keep bits past the 512th kept
// row are unobservable -> stop scanning once cnt >= MAXDET. Exact.
#define NMS_THREADS 256
__global__ __launch_bounds__(NMS_THREADS) void k_nms(const uint64_t* __restrict__ keys,
                                                     const float* __restrict__ sboxes,
                                                     const uint64_t* __restrict__ sup,
                                                     int* __restrict__ kidx,
                                                     int* __restrict__ kcount,
                                                     float* __restrict__ out_box,
                                                     float* __restrict__ out_conf) {
    __shared__ uint64_t buf[2][64 * WPR];   // 2 x 16 KB
    __shared__ uint8_t  val[NN];            // 2 KB
    __shared__ uint64_t kmaskS[WPR];
    __shared__ int pfx[WPR];
    __shared__ int s_kc;
    __shared__ int s_done;
    int b = blockIdx.x, t = threadIdx.x;
    const uint64_t* supb = sup + (size_t)b * NN * WPR;
    const uint64_t* keyb = keys + (size_t)b * NN;

    for (int i = t; i < NN; i += NMS_THREADS)
        val[i] = (uint8_t)((uint32_t)(keyb[i] >> 32) > ORD_HALF);  // conf > 0.5f
    if (t < WPR) kmaskS[t] = 0;
    if (t == 0) s_done = 0;
    for (int w = t; w < 64 * WPR; w += NMS_THREADS)   // stage group 0
        buf[0][w] = supb[w];
    __syncthreads();

    int wave = t >> 6;
    uint64_t kb = 0;      // lane l (wave 0) owns removed-word l
    int cnt = 0;
    if (t < 32) {
        uint64_t vm = 0;
#pragma unroll
        for (int c = 0; c < 64; ++c)
            vm |= ((uint64_t)val[(t << 6) | c]) << c;
        kb = ~vm;         // invalid = pre-removed
    }

    for (int g = 0; g < WPR; ++g) {
        if (wave > 0) {
            if (g + 1 < WPR) {                      // stage next group
                const uint64_t* src = supb + (size_t)(g + 1) * 64 * WPR;
                uint64_t* dst = buf[(g + 1) & 1];
                for (int w = t - 64; w < 64 * WPR; w += (NMS_THREADS - 64))
                    dst[w] = src[w];
            }
        } else if (t < 32) {
            const int l = t;
            const uint64_t* bufc = buf[g & 1];
            uint64_t rw = __shfl(kb, g);            // removed word for this group
            uint64_t gm = 0;                        // kept mask (uniform in lanes)
#pragma unroll
            for (int c = 0; c < 64; ++c) {
                uint64_t rowg = bufc[c * WPR + g];  // broadcast read
                uint64_t rowl = bufc[c * WPR + l];  // lane's own word
                bool kept = (((rw >> c) & 1ull) == 0);
                if (kept) {
                    rw |= rowg;                     // in-group suppression
                    kb |= rowl;                     // lane's word suppression
                    gm |= (1ull << c);
                }
            }
            if (l == g) kmaskS[g] = gm;
            cnt += __popcll(gm);
            if (cnt >= MAXDET) s_done = 1;          // uniform across lanes
        }
        __syncthreads();                            // staging done + flag visible
        if (s_done) break;
    }

    if (t == 0) {
        int s = 0;
        for (int w2 = 0; w2 < WPR; ++w2) { pfx[w2] = s; s += __popcll(kmaskS[w2]); }
        s_kc = (s < MAXDET) ? s : MAXDET;
        kcount[b] = s_kc;
    }
    __syncthreads();
    for (int i = t; i < NN; i += NMS_THREADS) {
        uint64_t m = kmaskS[i >> 6];
        if ((m >> (i & 63)) & 1ull) {
            int rank = pfx[i >> 6] + __popcll(m & ((1ull << (i & 63)) - 1ull));
            if (rank < MAXDET) {
                ((float4*)out_box)[(size_t)b * MAXDET + rank] =
                    ((const float4*)sboxes)[(size_t)b * NN + i];
                uint64_t kk = keyb[i];
                uint32_t u = (uint32_t)(kk >> 32);
                float cf = (u & 0x80000000u) ? __uint_as_float(u ^ 0x80000000u)
                                             : __uint_as_float(~u);
                out_conf[(size_t)b * MAXDET + rank] = cf;
                kidx[b * MAXDET + rank] = (NN - 1) - (int)(kk & 0xFFFFFFFFull);
            }
        }
    }
    for (int k = s_kc + t; k < MAXDET; k += NMS_THREADS) {
        ((float4*)out_box)[(size_t)b * MAXDET + k] = make_float4(0.f, 0.f, 0.f, 0.f);
        out_conf[(size_t)b * MAXDET + k] = 0.0f;
    }
}

// Kernel 4: softmax gather for kept rows; zero-fill the rest. One wave per slot.
__global__ void k_softmax(const float* __restrict__ cls, const int* __restrict__ kidx,
                          const int* __restrict__ kcount, float* __restrict__ out_cls) {
    int k = blockIdx.x, b = blockIdx.y, lane = threadIdx.x;  // 64 threads
    float* dst = out_cls + ((size_t)b * MAXDET + k) * NC;
    if (k >= kcount[b]) {
        dst[lane] = 0.0f;
        if (lane < NC - 64) dst[64 + lane] = 0.0f;
        return;
    }
    int n = kidx[b * MAXDET + k];
    const float* src = cls + ((size_t)b * NN + n) * NC;
    float x0 = src[lane];
    float x1 = (lane < NC - 64) ? src[64 + lane] : -3.0e38f;
    float m = fmaxf(x0, x1);
    for (int o = 32; o > 0; o >>= 1) m = fmaxf(m, __shfl_xor(m, o));
    float e0 = expf(x0 - m);
    float e1 = (lane < NC - 64) ? expf(x1 - m) : 0.0f;
    float s = e0 + e1;
    for (int o = 32; o > 0; o >>= 1) s += __shfl_xor(s, o);
    dst[lane] = e0 / s;
    if (lane < NC - 64) dst[64 + lane] = e1 / s;
}

extern "C" void kernel_launch(void* const* d_in, const int* in_sizes, int n_in,
                              void* d_out, int out_size, void* d_ws, size_t ws_size,
                              hipStream_t stream) {
    const float* boxes = (const float*)d_in[0];   // [8][2048][4]
    const float* cls   = (const float*)d_in[1];   // [8][2048][80]
    float* out      = (float*)d_out;
    float* out_box  = out;                          // [8][512][4]
    float* out_cls  = out + BB * MAXDET * 4;        // [8][512][80]
    float* out_conf = out + BB * MAXDET * (4 + NC); // [8][512]

    char* ws = (char*)d_ws;
    uint64_t* keysA  = (uint64_t*)(ws + 0);
    uint64_t* keysB  = (uint64_t*)(ws + 131072);
    float*    sboxes = (float*)(ws + 262144);
    int*      kidx   = (int*)(ws + 524288);
    int*      kcount = (int*)(ws + 540672);
    uint64_t* sup    = (uint64_t*)(ws + 544768);

    k_conf<<<(BB * NN) / 256, 256, 0, stream>>>(cls, keysA);
    k_rank<<<BB, 1024, 0, stream>>>(keysA, keysB, boxes, sboxes);
    k_sup<<<dim3(NN / 64, NN / 256, BB), 256, 0, stream>>>(sboxes, sup);
    k_nms<<<BB, NMS_THREADS, 0, stream>>>(keysB, sboxes, sup, kidx, kcount, out_box, out_conf);
    k_softmax<<<dim3(MAXDET, BB), 64, 0, stream>>>(cls, kidx, kcount, out_cls);
}

// Round 6
// 90.774 us; speedup vs baseline: 3.0175x; 1.7286x over previous
//
#include <hip/hip_runtime.h>
#include <stdint.h>

#define BB 8
#define NN 2048
#define NC 80
#define MAXDET 512
#define WPR 32            // 64-bit words per row of the suppression matrix (2048/64)

// ---------------- ws layout (bytes) ----------------
// keysA  : uint64 [BB][NN]        @ 0        (131072)   unsorted keys
// keysB  : uint64 [BB][NN]        @ 131072   (131072)   sorted keys
// sboxes : float  [BB][NN][4]     @ 262144   (262144)
// kidx   : int32  [BB][MAXDET]    @ 524288   (16384)
// kcount : int32  [BB]            @ 540672   (128 pad)
// sup    : uint64 [BB][NN][WPR]   @ 544768   (4194304)
// total ~4.52 MB

#define ORD_HALF 0xBF000000u   // orderable(0.5f)

// Kernel 0: conf = 1/(1+expf(-max_logit)) computed step-by-step in f32
// (matches numpy/XLA f32 sigmoid rounding chain, hence its tie GROUPING).
// key = orderable(conf) << 32 | (N-1-n): descending conf, ties -> smaller n.
__global__ void k_conf(const float* __restrict__ cls, uint64_t* __restrict__ keys) {
    int gid = blockIdx.x * blockDim.x + threadIdx.x;      // 0 .. BB*NN-1
    const float4* p = (const float4*)(cls + (size_t)gid * NC);
    float m = -3.0e38f;
#pragma unroll
    for (int i = 0; i < NC / 4; ++i) {
        float4 v = p[i];
        m = fmaxf(m, fmaxf(fmaxf(v.x, v.y), fmaxf(v.z, v.w)));
    }
    float e  = expf(-m);                 // f32
    float cf = 1.0f / (1.0f + e);        // f32 step-by-step
    uint32_t u = __float_as_uint(cf);
    u = (u & 0x80000000u) ? ~u : (u | 0x80000000u);       // monotone float->uint map
    int n = gid & (NN - 1);
    keys[gid] = ((uint64_t)u << 32) | (uint32_t)(NN - 1 - n);
}

// Kernel 1: parallel rank sort. rank = #{m : key[m] > key[n]} (keys distinct
// via embedded index -> exact permutation). Block = 512 threads handles 128
// elements of one batch; each element's 2048-key scan is split across 4
// threads (512 keys each, wave-uniform index -> LDS broadcast reads).
#define RCHUNK 128
__global__ __launch_bounds__(512) void k_rank(const uint64_t* __restrict__ keys_in,
                                              uint64_t* __restrict__ keys_out,
                                              const float* __restrict__ boxes,
                                              float* __restrict__ sboxes) {
    __shared__ uint64_t sk[NN];              // 16 KB
    __shared__ uint16_t part[4][RCHUNK];     // 1 KB
    int b = blockIdx.y, t = threadIdx.x;
    const uint64_t* kin = keys_in + (size_t)b * NN;
#pragma unroll
    for (int j = 0; j < NN / 512; ++j)
        sk[t + j * 512] = kin[t + j * 512];
    __syncthreads();
    int sub = t >> 7;                        // scan quarter 0..3 (uniform per wave)
    int el  = t & (RCHUNK - 1);              // element within chunk
    int e   = blockIdx.x * RCHUNK + el;
    uint64_t mykey = sk[e];
    int base = sub * (NN / 4);
    int r = 0;
    for (int mm = 0; mm < NN / 4; ++mm)
        r += (sk[base + mm] > mykey) ? 1 : 0;
    part[sub][el] = (uint16_t)r;
    __syncthreads();
    if (t < RCHUNK) {
        int rank = part[0][t] + part[1][t] + part[2][t] + part[3][t];
        keys_out[(size_t)b * NN + rank] = mykey;
        int orig = (NN - 1) - (int)(mykey & 0xFFFFFFFFull);
        ((float4*)sboxes)[(size_t)b * NN + rank] =
            ((const float4*)boxes)[(size_t)b * NN + orig];
    }
}

// Kernel 2: suppression bit matrix (unchanged). Block = 64-row x 256-col tile.
// Bit c of word gw of row r: IoU(r, col) > 0.5 && col > r.
__global__ void k_sup(const float* __restrict__ sboxes, uint64_t* __restrict__ sup) {
#pragma clang fp contract(off)
    __shared__ float cy1[256], cx1[256], cy2[256], cx2[256], car[256];
    __shared__ float ry1[64], rx1[64], ry2[64], rx2[64], rar[64];
    int rt = blockIdx.x, ct = blockIdx.y, b = blockIdx.z;
    int t = threadIdx.x;
    int col0 = ct << 8, row0 = rt << 6;
    {
        float4 bx = ((const float4*)sboxes)[(size_t)b * NN + col0 + t];
        cy1[t] = bx.x; cx1[t] = bx.y; cy2[t] = bx.z; cx2[t] = bx.w;
        car[t] = (bx.z - bx.x) * (bx.w - bx.y);
        if (t < 64) {
            float4 rb = ((const float4*)sboxes)[(size_t)b * NN + row0 + t];
            ry1[t] = rb.x; rx1[t] = rb.y; ry2[t] = rb.z; rx2[t] = rb.w;
            rar[t] = (rb.z - rb.x) * (rb.w - rb.y);
        }
    }
    __syncthreads();
    int lr = t & 63, lg = t >> 6;
    int r = row0 + lr;
    int gw = (ct << 2) + lg;
    int cbase = gw << 6;
    uint64_t w = 0;
    if (cbase + 63 > r) {                  // tile not entirely at/below diagonal
        float y1 = ry1[lr], x1 = rx1[lr], y2 = ry2[lr], x2 = rx2[lr], ar = rar[lr];
        int lcb = lg << 6;
        for (int c = 0; c < 64; ++c) {
            int lc = lcb + c;
            float ih = fmaxf(fminf(y2, cy2[lc]) - fmaxf(y1, cy1[lc]), 0.0f);
            float iw = fmaxf(fminf(x2, cx2[lc]) - fmaxf(x1, cx1[lc]), 0.0f);
            float inter = ih * iw;
            float uni = (ar + car[lc]) - inter;
            float iou = inter / fmaxf(uni, 1e-9f);
            if ((iou > 0.5f) & ((cbase + c) > r)) w |= (1ull << c);
        }
    }
    sup[((size_t)b * NN + r) * WPR + gw] = w;
}

// Kernel 3: greedy scan, LDS-staged double-buffer + exact early exit.
// 256 threads: wave 0 lanes 0..31 scan group g from buf[g&1]; waves 1..3
// stage group g+1 (16 KB) into buf[(g+1)&1]. One barrier per group.
// Early exit: output only consumes the first MAXDET kept rows (top_k of a
// descending-sorted masked score vector), so keep bits past the 512th kept
// row are unobservable -> stop scanning once cnt >= MAXDET. Exact.
#define NMS_THREADS 256
__global__ __launch_bounds__(NMS_THREADS) void k_nms(const uint64_t* __restrict__ keys,
                                                     const float* __restrict__ sboxes,
                                                     const uint64_t* __restrict__ sup,
                                                     int* __restrict__ kidx,
                                                     int* __restrict__ kcount,
                                                     float* __restrict__ out_box,
                                                     float* __restrict__ out_conf) {
    __shared__ uint64_t buf[2][64 * WPR];   // 2 x 16 KB
    __shared__ uint8_t  val[NN];            // 2 KB
    __shared__ uint64_t kmaskS[WPR];
    __shared__ int pfx[WPR];
    __shared__ int s_kc;
    __shared__ int s_done;
    int b = blockIdx.x, t = threadIdx.x;
    const uint64_t* supb = sup + (size_t)b * NN * WPR;
    const uint64_t* keyb = keys + (size_t)b * NN;

    for (int i = t; i < NN; i += NMS_THREADS)
        val[i] = (uint8_t)((uint32_t)(keyb[i] >> 32) > ORD_HALF);  // conf > 0.5f
    if (t < WPR) kmaskS[t] = 0;
    if (t == 0) s_done = 0;
    for (int w = t; w < 64 * WPR; w += NMS_THREADS)   // stage group 0
        buf[0][w] = supb[w];
    __syncthreads();

    int wave = t >> 6;
    uint64_t kb = 0;      // lane l (wave 0) owns removed-word l
    int cnt = 0;
    if (t < 32) {
        uint64_t vm = 0;
#pragma unroll
        for (int c = 0; c < 64; ++c)
            vm |= ((uint64_t)val[(t << 6) | c]) << c;
        kb = ~vm;         // invalid = pre-removed
    }

    for (int g = 0; g < WPR; ++g) {
        if (wave > 0) {
            if (g + 1 < WPR) {                      // stage next group
                const uint64_t* src = supb + (size_t)(g + 1) * 64 * WPR;
                uint64_t* dst = buf[(g + 1) & 1];
                for (int w = t - 64; w < 64 * WPR; w += (NMS_THREADS - 64))
                    dst[w] = src[w];
            }
        } else if (t < 32) {
            const int l = t;
            const uint64_t* bufc = buf[g & 1];
            uint64_t rw = __shfl(kb, g);            // removed word for this group
            uint64_t gm = 0;                        // kept mask (uniform in lanes)
#pragma unroll
            for (int c = 0; c < 64; ++c) {
                uint64_t rowg = bufc[c * WPR + g];  // broadcast read
                uint64_t rowl = bufc[c * WPR + l];  // lane's own word
                bool kept = (((rw >> c) & 1ull) == 0);
                if (kept) {
                    rw |= rowg;                     // in-group suppression
                    kb |= rowl;                     // lane's word suppression
                    gm |= (1ull << c);
                }
            }
            if (l == g) kmaskS[g] = gm;
            cnt += __popcll(gm);
            if (cnt >= MAXDET) s_done = 1;          // uniform across lanes
        }
        __syncthreads();                            // staging done + flag visible
        if (s_done) break;
    }

    if (t == 0) {
        int s = 0;
        for (int w2 = 0; w2 < WPR; ++w2) { pfx[w2] = s; s += __popcll(kmaskS[w2]); }
        s_kc = (s < MAXDET) ? s : MAXDET;
        kcount[b] = s_kc;
    }
    __syncthreads();
    for (int i = t; i < NN; i += NMS_THREADS) {
        uint64_t m = kmaskS[i >> 6];
        if ((m >> (i & 63)) & 1ull) {
            int rank = pfx[i >> 6] + __popcll(m & ((1ull << (i & 63)) - 1ull));
            if (rank < MAXDET) {
                ((float4*)out_box)[(size_t)b * MAXDET + rank] =
                    ((const float4*)sboxes)[(size_t)b * NN + i];
                uint64_t kk = keyb[i];
                uint32_t u = (uint32_t)(kk >> 32);
                float cf = (u & 0x80000000u) ? __uint_as_float(u ^ 0x80000000u)
                                             : __uint_as_float(~u);
                out_conf[(size_t)b * MAXDET + rank] = cf;
                kidx[b * MAXDET + rank] = (NN - 1) - (int)(kk & 0xFFFFFFFFull);
            }
        }
    }
    for (int k = s_kc + t; k < MAXDET; k += NMS_THREADS) {
        ((float4*)out_box)[(size_t)b * MAXDET + k] = make_float4(0.f, 0.f, 0.f, 0.f);
        out_conf[(size_t)b * MAXDET + k] = 0.0f;
    }
}

// Kernel 4: softmax gather for kept rows; zero-fill the rest. One wave per slot.
__global__ void k_softmax(const float* __restrict__ cls, const int* __restrict__ kidx,
                          const int* __restrict__ kcount, float* __restrict__ out_cls) {
    int k = blockIdx.x, b = blockIdx.y, lane = threadIdx.x;  // 64 threads
    float* dst = out_cls + ((size_t)b * MAXDET + k) * NC;
    if (k >= kcount[b]) {
        dst[lane] = 0.0f;
        if (lane < NC - 64) dst[64 + lane] = 0.0f;
        return;
    }
    int n = kidx[b * MAXDET + k];
    const float* src = cls + ((size_t)b * NN + n) * NC;
    float x0 = src[lane];
    float x1 = (lane < NC - 64) ? src[64 + lane] : -3.0e38f;
    float m = fmaxf(x0, x1);
    for (int o = 32; o > 0; o >>= 1) m = fmaxf(m, __shfl_xor(m, o));
    float e0 = expf(x0 - m);
    float e1 = (lane < NC - 64) ? expf(x1 - m) : 0.0f;
    float s = e0 + e1;
    for (int o = 32; o > 0; o >>= 1) s += __shfl_xor(s, o);
    dst[lane] = e0 / s;
    if (lane < NC - 64) dst[64 + lane] = e1 / s;
}

extern "C" void kernel_launch(void* const* d_in, const int* in_sizes, int n_in,
                              void* d_out, int out_size, void* d_ws, size_t ws_size,
                              hipStream_t stream) {
    const float* boxes = (const float*)d_in[0];   // [8][2048][4]
    const float* cls   = (const float*)d_in[1];   // [8][2048][80]
    float* out      = (float*)d_out;
    float* out_box  = out;                          // [8][512][4]
    float* out_cls  = out + BB * MAXDET * 4;        // [8][512][80]
    float* out_conf = out + BB * MAXDET * (4 + NC); // [8][512]

    char* ws = (char*)d_ws;
    uint64_t* keysA  = (uint64_t*)(ws + 0);
    uint64_t* keysB  = (uint64_t*)(ws + 131072);
    float*    sboxes = (float*)(ws + 262144);
    int*      kidx   = (int*)(ws + 524288);
    int*      kcount = (int*)(ws + 540672);
    uint64_t* sup    = (uint64_t*)(ws + 544768);

    k_conf<<<(BB * NN) / 256, 256, 0, stream>>>(cls, keysA);
    k_rank<<<dim3(NN / RCHUNK, BB), 512, 0, stream>>>(keysA, keysB, boxes, sboxes);
    k_sup<<<dim3(NN / 64, NN / 256, BB), 256, 0, stream>>>(sboxes, sup);
    k_nms<<<BB, NMS_THREADS, 0, stream>>>(keysB, sboxes, sup, kidx, kcount, out_box, out_conf);
    k_softmax<<<dim3(MAXDET, BB), 64, 0, stream>>>(cls, kidx, kcount, out_cls);
}

// Round 7
// 88.823 us; speedup vs baseline: 3.0838x; 1.0220x over previous
//
#include <hip/hip_runtime.h>
#include <stdint.h>

#define BB 8
#define NN 2048
#define NC 80
#define MAXDET 512
#define WPR 32            // 64-bit words per row of the suppression matrix (2048/64)

// ---------------- ws layout (bytes) ----------------
// keysA  : uint64 [BB][NN]        @ 0        (131072)   unsorted keys
// keysB  : uint64 [BB][NN]        @ 131072   (131072)   sorted keys
// sboxes : float  [BB][NN][4]     @ 262144   (262144)
// kidx   : int32  [BB][MAXDET]    @ 524288   (16384)
// kcount : int32  [BB]            @ 540672   (128 pad)
// sup    : uint64 [BB][NN][WPR]   @ 544768   (4194304)
// total ~4.52 MB

#define ORD_HALF 0xBF000000u   // orderable(0.5f)

// Kernel 0: conf = 1/(1+expf(-max_logit)) computed step-by-step in f32
// (matches numpy/XLA f32 sigmoid rounding chain, hence its tie GROUPING).
// key = orderable(conf) << 32 | (N-1-n): descending conf, ties -> smaller n.
__global__ void k_conf(const float* __restrict__ cls, uint64_t* __restrict__ keys) {
    int gid = blockIdx.x * blockDim.x + threadIdx.x;      // 0 .. BB*NN-1
    const float4* p = (const float4*)(cls + (size_t)gid * NC);
    float m = -3.0e38f;
#pragma unroll
    for (int i = 0; i < NC / 4; ++i) {
        float4 v = p[i];
        m = fmaxf(m, fmaxf(fmaxf(v.x, v.y), fmaxf(v.z, v.w)));
    }
    float e  = expf(-m);                 // f32
    float cf = 1.0f / (1.0f + e);        // f32 step-by-step
    uint32_t u = __float_as_uint(cf);
    u = (u & 0x80000000u) ? ~u : (u | 0x80000000u);       // monotone float->uint map
    int n = gid & (NN - 1);
    keys[gid] = ((uint64_t)u << 32) | (uint32_t)(NN - 1 - n);
}

// Kernel 1: parallel rank sort. rank = #{m : key[m] > key[n]} (keys distinct
// via embedded index -> exact permutation). Block = 512 threads handles 128
// elements of one batch; each element's 2048-key scan is split across 4
// threads (512 keys each, wave-uniform index -> LDS broadcast reads).
#define RCHUNK 128
__global__ __launch_bounds__(512) void k_rank(const uint64_t* __restrict__ keys_in,
                                              uint64_t* __restrict__ keys_out,
                                              const float* __restrict__ boxes,
                                              float* __restrict__ sboxes) {
    __shared__ uint64_t sk[NN];              // 16 KB
    __shared__ uint16_t part[4][RCHUNK];     // 1 KB
    int b = blockIdx.y, t = threadIdx.x;
    const uint64_t* kin = keys_in + (size_t)b * NN;
#pragma unroll
    for (int j = 0; j < NN / 512; ++j)
        sk[t + j * 512] = kin[t + j * 512];
    __syncthreads();
    int sub = t >> 7;                        // scan quarter 0..3 (uniform per wave)
    int el  = t & (RCHUNK - 1);              // element within chunk
    int e   = blockIdx.x * RCHUNK + el;
    uint64_t mykey = sk[e];
    int base = sub * (NN / 4);
    int r = 0;
    for (int mm = 0; mm < NN / 4; ++mm)
        r += (sk[base + mm] > mykey) ? 1 : 0;
    part[sub][el] = (uint16_t)r;
    __syncthreads();
    if (t < RCHUNK) {
        int rank = part[0][t] + part[1][t] + part[2][t] + part[3][t];
        keys_out[(size_t)b * NN + rank] = mykey;
        int orig = (NN - 1) - (int)(mykey & 0xFFFFFFFFull);
        ((float4*)sboxes)[(size_t)b * NN + rank] =
            ((const float4*)boxes)[(size_t)b * NN + orig];
    }
}

// Kernel 2: suppression bit matrix (unchanged). Block = 64-row x 256-col tile.
// Bit c of word gw of row r: IoU(r, col) > 0.5 && col > r.
__global__ void k_sup(const float* __restrict__ sboxes, uint64_t* __restrict__ sup) {
#pragma clang fp contract(off)
    __shared__ float cy1[256], cx1[256], cy2[256], cx2[256], car[256];
    __shared__ float ry1[64], rx1[64], ry2[64], rx2[64], rar[64];
    int rt = blockIdx.x, ct = blockIdx.y, b = blockIdx.z;
    int t = threadIdx.x;
    int col0 = ct << 8, row0 = rt << 6;
    {
        float4 bx = ((const float4*)sboxes)[(size_t)b * NN + col0 + t];
        cy1[t] = bx.x; cx1[t] = bx.y; cy2[t] = bx.z; cx2[t] = bx.w;
        car[t] = (bx.z - bx.x) * (bx.w - bx.y);
        if (t < 64) {
            float4 rb = ((const float4*)sboxes)[(size_t)b * NN + row0 + t];
            ry1[t] = rb.x; rx1[t] = rb.y; ry2[t] = rb.z; rx2[t] = rb.w;
            rar[t] = (rb.z - rb.x) * (rb.w - rb.y);
        }
    }
    __syncthreads();
    int lr = t & 63, lg = t >> 6;
    int r = row0 + lr;
    int gw = (ct << 2) + lg;
    int cbase = gw << 6;
    uint64_t w = 0;
    if (cbase + 63 > r) {                  // tile not entirely at/below diagonal
        float y1 = ry1[lr], x1 = rx1[lr], y2 = ry2[lr], x2 = rx2[lr], ar = rar[lr];
        int lcb = lg << 6;
        for (int c = 0; c < 64; ++c) {
            int lc = lcb + c;
            float ih = fmaxf(fminf(y2, cy2[lc]) - fmaxf(y1, cy1[lc]), 0.0f);
            float iw = fmaxf(fminf(x2, cx2[lc]) - fmaxf(x1, cx1[lc]), 0.0f);
            float inter = ih * iw;
            float uni = (ar + car[lc]) - inter;
            float iou = inter / fmaxf(uni, 1e-9f);
            if ((iou > 0.5f) & ((cbase + c) > r)) w |= (1ull << c);
        }
    }
    sup[((size_t)b * NN + r) * WPR + gw] = w;
}

// Kernel 3: greedy scan, LDS double-buffer, register-staged prefetch, early exit.
// 320 threads (5 waves): wave 0 lanes 0..31 scan group g from buf[g&1];
// waves 1..4 (256 threads) stage group g+1: each thread 4 independent
// global_load_dwordx4 into regs, then 4 ds_write_b128 (one round-trip/group,
// overlapped with the scan). One barrier per group.
// Early exit: output only consumes the first MAXDET kept rows -> stop once
// cnt >= MAXDET. Exact (kmask pre-zeroed, kcount clamps).
#define NMS_THREADS 320
__global__ __launch_bounds__(NMS_THREADS) void k_nms(const uint64_t* __restrict__ keys,
                                                     const float* __restrict__ sboxes,
                                                     const uint64_t* __restrict__ sup,
                                                     int* __restrict__ kidx,
                                                     int* __restrict__ kcount,
                                                     float* __restrict__ out_box,
                                                     float* __restrict__ out_conf) {
    __shared__ uint64_t buf[2][64 * WPR];   // 2 x 16 KB
    __shared__ uint8_t  val[NN];            // 2 KB
    __shared__ uint64_t kmaskS[WPR];
    __shared__ int pfx[WPR];
    __shared__ int s_kc;
    __shared__ int s_done;
    int b = blockIdx.x, t = threadIdx.x;
    const uint64_t* supb = sup + (size_t)b * NN * WPR;
    const uint64_t* keyb = keys + (size_t)b * NN;

    for (int i = t; i < NN; i += NMS_THREADS)
        val[i] = (uint8_t)((uint32_t)(keyb[i] >> 32) > ORD_HALF);  // conf > 0.5f
    if (t < WPR) kmaskS[t] = 0;
    if (t == 0) s_done = 0;
    for (int w = t; w < 64 * WPR / 2; w += NMS_THREADS)   // stage group 0 (16B units)
        ((float4*)buf[0])[w] = ((const float4*)supb)[w];
    __syncthreads();

    int wave = t >> 6;
    uint64_t kb = 0;      // lane l (wave 0) owns removed-word l
    int cnt = 0;
    if (t < 32) {
        uint64_t vm = 0;
#pragma unroll
        for (int c = 0; c < 64; ++c)
            vm |= ((uint64_t)val[(t << 6) | c]) << c;
        kb = ~vm;         // invalid = pre-removed
    }

    for (int g = 0; g < WPR; ++g) {
        if (wave > 0) {
            if (g + 1 < WPR) {                      // stage next group: 1024 x 16B
                const float4* src = (const float4*)(supb + (size_t)(g + 1) * 64 * WPR);
                float4* dst = (float4*)buf[(g + 1) & 1];
                int idx = t - 64;                   // 0..255
                float4 r0 = src[idx];
                float4 r1 = src[idx + 256];
                float4 r2 = src[idx + 512];
                float4 r3 = src[idx + 768];
                dst[idx]       = r0;
                dst[idx + 256] = r1;
                dst[idx + 512] = r2;
                dst[idx + 768] = r3;
            }
        } else if (t < 32) {
            const int l = t;
            const uint64_t* bufc = buf[g & 1];
            uint64_t rw = __shfl(kb, g);            // removed word for this group
            uint64_t gm = 0;                        // kept mask (uniform in lanes)
#pragma unroll
            for (int c = 0; c < 64; ++c) {
                uint64_t rowg = bufc[c * WPR + g];  // broadcast read
                uint64_t rowl = bufc[c * WPR + l];  // lane's own word
                bool kept = (((rw >> c) & 1ull) == 0);
                if (kept) {
                    rw |= rowg;                     // in-group suppression
                    kb |= rowl;                     // lane's word suppression
                    gm |= (1ull << c);
                }
            }
            if (l == g) kmaskS[g] = gm;
            cnt += __popcll(gm);
            if (cnt >= MAXDET) s_done = 1;          // uniform across lanes
        }
        __syncthreads();                            // staging done + flag visible
        if (s_done) break;
    }

    if (t == 0) {
        int s = 0;
        for (int w2 = 0; w2 < WPR; ++w2) { pfx[w2] = s; s += __popcll(kmaskS[w2]); }
        s_kc = (s < MAXDET) ? s : MAXDET;
        kcount[b] = s_kc;
    }
    __syncthreads();
    for (int i = t; i < NN; i += NMS_THREADS) {
        uint64_t m = kmaskS[i >> 6];
        if ((m >> (i & 63)) & 1ull) {
            int rank = pfx[i >> 6] + __popcll(m & ((1ull << (i & 63)) - 1ull));
            if (rank < MAXDET) {
                ((float4*)out_box)[(size_t)b * MAXDET + rank] =
                    ((const float4*)sboxes)[(size_t)b * NN + i];
                uint64_t kk = keyb[i];
                uint32_t u = (uint32_t)(kk >> 32);
                float cf = (u & 0x80000000u) ? __uint_as_float(u ^ 0x80000000u)
                                             : __uint_as_float(~u);
                out_conf[(size_t)b * MAXDET + rank] = cf;
                kidx[b * MAXDET + rank] = (NN - 1) - (int)(kk & 0xFFFFFFFFull);
            }
        }
    }
    for (int k = s_kc + t; k < MAXDET; k += NMS_THREADS) {
        ((float4*)out_box)[(size_t)b * MAXDET + k] = make_float4(0.f, 0.f, 0.f, 0.f);
        out_conf[(size_t)b * MAXDET + k] = 0.0f;
    }
}

// Kernel 4: softmax gather for kept rows; zero-fill the rest. One wave per slot.
__global__ void k_softmax(const float* __restrict__ cls, const int* __restrict__ kidx,
                          const int* __restrict__ kcount, float* __restrict__ out_cls) {
    int k = blockIdx.x, b = blockIdx.y, lane = threadIdx.x;  // 64 threads
    float* dst = out_cls + ((size_t)b * MAXDET + k) * NC;
    if (k >= kcount[b]) {
        dst[lane] = 0.0f;
        if (lane < NC - 64) dst[64 + lane] = 0.0f;
        return;
    }
    int n = kidx[b * MAXDET + k];
    const float* src = cls + ((size_t)b * NN + n) * NC;
    float x0 = src[lane];
    float x1 = (lane < NC - 64) ? src[64 + lane] : -3.0e38f;
    float m = fmaxf(x0, x1);
    for (int o = 32; o > 0; o >>= 1) m = fmaxf(m, __shfl_xor(m, o));
    float e0 = expf(x0 - m);
    float e1 = (lane < NC - 64) ? expf(x1 - m) : 0.0f;
    float s = e0 + e1;
    for (int o = 32; o > 0; o >>= 1) s += __shfl_xor(s, o);
    dst[lane] = e0 / s;
    if (lane < NC - 64) dst[64 + lane] = e1 / s;
}

extern "C" void kernel_launch(void* const* d_in, const int* in_sizes, int n_in,
                              void* d_out, int out_size, void* d_ws, size_t ws_size,
                              hipStream_t stream) {
    const float* boxes = (const float*)d_in[0];   // [8][2048][4]
    const float* cls   = (const float*)d_in[1];   // [8][2048][80]
    float* out      = (float*)d_out;
    float* out_box  = out;                          // [8][512][4]
    float* out_cls  = out + BB * MAXDET * 4;        // [8][512][80]
    float* out_conf = out + BB * MAXDET * (4 + NC); // [8][512]

    char* ws = (char*)d_ws;
    uint64_t* keysA  = (uint64_t*)(ws + 0);
    uint64_t* keysB  = (uint64_t*)(ws + 131072);
    float*    sboxes = (float*)(ws + 262144);
    int*      kidx   = (int*)(ws + 524288);
    int*      kcount = (int*)(ws + 540672);
    uint64_t* sup    = (uint64_t*)(ws + 544768);

    k_conf<<<(BB * NN) / 256, 256, 0, stream>>>(cls, keysA);
    k_rank<<<dim3(NN / RCHUNK, BB), 512, 0, stream>>>(keysA, keysB, boxes, sboxes);
    k_sup<<<dim3(NN / 64, NN / 256, BB), 256, 0, stream>>>(sboxes, sup);
    k_nms<<<BB, NMS_THREADS, 0, stream>>>(keysB, sboxes, sup, kidx, kcount, out_box, out_conf);
    k_softmax<<<dim3(MAXDET, BB), 64, 0, stream>>>(cls, kidx, kcount, out_cls);
}

// Round 8
// 85.561 us; speedup vs baseline: 3.2014x; 1.0381x over previous
//
#include <hip/hip_runtime.h>
#include <stdint.h>

#define BB 8
#define NN 2048
#define NC 80
#define MAXDET 512
#define WPR 32            // 64-bit words per row of the suppression matrix (2048/64)

// ---------------- ws layout (bytes) ----------------
// keysA  : uint64 [BB][NN]        @ 0        (131072)   unsorted keys
// keysB  : uint64 [BB][NN]        @ 131072   (131072)   sorted keys
// sboxes : float  [BB][NN][4]     @ 262144   (262144)
// kidx   : int32  [BB][MAXDET]    @ 524288   (16384)
// kcount : int32  [BB]            @ 540672   (128 pad)
// sup    : uint64 [BB][NN][WPR]   @ 544768   (4194304)
// total ~4.52 MB

#define ORD_HALF 0xBF000000u   // orderable(0.5f)

// Kernel 0: conf = 1/(1+expf(-max_logit)) computed step-by-step in f32
// (matches numpy/XLA f32 sigmoid rounding chain, hence its tie GROUPING).
// key = orderable(conf) << 32 | (N-1-n): descending conf, ties -> smaller n.
__global__ void k_conf(const float* __restrict__ cls, uint64_t* __restrict__ keys) {
    int gid = blockIdx.x * blockDim.x + threadIdx.x;      // 0 .. BB*NN-1
    const float4* p = (const float4*)(cls + (size_t)gid * NC);
    float m = -3.0e38f;
#pragma unroll
    for (int i = 0; i < NC / 4; ++i) {
        float4 v = p[i];
        m = fmaxf(m, fmaxf(fmaxf(v.x, v.y), fmaxf(v.z, v.w)));
    }
    float e  = expf(-m);                 // f32
    float cf = 1.0f / (1.0f + e);        // f32 step-by-step
    uint32_t u = __float_as_uint(cf);
    u = (u & 0x80000000u) ? ~u : (u | 0x80000000u);       // monotone float->uint map
    int n = gid & (NN - 1);
    keys[gid] = ((uint64_t)u << 32) | (uint32_t)(NN - 1 - n);
}

// Kernel 1: parallel rank sort. rank = #{m : key[m] > key[n]} (keys distinct
// via embedded index -> exact permutation). Block = 512 threads handles 128
// elements of one batch; each element's 2048-key scan is split across 4
// threads (512 keys each, wave-uniform index -> LDS broadcast reads).
#define RCHUNK 128
__global__ __launch_bounds__(512) void k_rank(const uint64_t* __restrict__ keys_in,
                                              uint64_t* __restrict__ keys_out,
                                              const float* __restrict__ boxes,
                                              float* __restrict__ sboxes) {
    __shared__ uint64_t sk[NN];              // 16 KB
    __shared__ uint16_t part[4][RCHUNK];     // 1 KB
    int b = blockIdx.y, t = threadIdx.x;
    const uint64_t* kin = keys_in + (size_t)b * NN;
#pragma unroll
    for (int j = 0; j < NN / 512; ++j)
        sk[t + j * 512] = kin[t + j * 512];
    __syncthreads();
    int sub = t >> 7;                        // scan quarter 0..3 (uniform per wave)
    int el  = t & (RCHUNK - 1);              // element within chunk
    int e   = blockIdx.x * RCHUNK + el;
    uint64_t mykey = sk[e];
    int base = sub * (NN / 4);
    int r = 0;
    for (int mm = 0; mm < NN / 4; ++mm)
        r += (sk[base + mm] > mykey) ? 1 : 0;
    part[sub][el] = (uint16_t)r;
    __syncthreads();
    if (t < RCHUNK) {
        int rank = part[0][t] + part[1][t] + part[2][t] + part[3][t];
        keys_out[(size_t)b * NN + rank] = mykey;
        int orig = (NN - 1) - (int)(mykey & 0xFFFFFFFFull);
        ((float4*)sboxes)[(size_t)b * NN + rank] =
            ((const float4*)boxes)[(size_t)b * NN + orig];
    }
}

// Kernel 2: suppression bit matrix (unchanged). Block = 64-row x 256-col tile.
// Bit c of word gw of row r: IoU(r, col) > 0.5 && col > r.
__global__ void k_sup(const float* __restrict__ sboxes, uint64_t* __restrict__ sup) {
#pragma clang fp contract(off)
    __shared__ float cy1[256], cx1[256], cy2[256], cx2[256], car[256];
    __shared__ float ry1[64], rx1[64], ry2[64], rx2[64], rar[64];
    int rt = blockIdx.x, ct = blockIdx.y, b = blockIdx.z;
    int t = threadIdx.x;
    int col0 = ct << 8, row0 = rt << 6;
    {
        float4 bx = ((const float4*)sboxes)[(size_t)b * NN + col0 + t];
        cy1[t] = bx.x; cx1[t] = bx.y; cy2[t] = bx.z; cx2[t] = bx.w;
        car[t] = (bx.z - bx.x) * (bx.w - bx.y);
        if (t < 64) {
            float4 rb = ((const float4*)sboxes)[(size_t)b * NN + row0 + t];
            ry1[t] = rb.x; rx1[t] = rb.y; ry2[t] = rb.z; rx2[t] = rb.w;
            rar[t] = (rb.z - rb.x) * (rb.w - rb.y);
        }
    }
    __syncthreads();
    int lr = t & 63, lg = t >> 6;
    int r = row0 + lr;
    int gw = (ct << 2) + lg;
    int cbase = gw << 6;
    uint64_t w = 0;
    if (cbase + 63 > r) {                  // tile not entirely at/below diagonal
        float y1 = ry1[lr], x1 = rx1[lr], y2 = ry2[lr], x2 = rx2[lr], ar = rar[lr];
        int lcb = lg << 6;
        for (int c = 0; c < 64; ++c) {
            int lc = lcb + c;
            float ih = fmaxf(fminf(y2, cy2[lc]) - fmaxf(y1, cy1[lc]), 0.0f);
            float iw = fmaxf(fminf(x2, cx2[lc]) - fmaxf(x1, cx1[lc]), 0.0f);
            float inter = ih * iw;
            float uni = (ar + car[lc]) - inter;
            float iou = inter / fmaxf(uni, 1e-9f);
            if ((iou > 0.5f) & ((cbase + c) > r)) w |= (1ull << c);
        }
    }
    sup[((size_t)b * NN + r) * WPR + gw] = w;
}

// Kernel 3: greedy scan. 320 threads (5 waves): wave 0 scans group g from
// buf[g&1]; waves 1..4 stage group g+1 with 4 independent dwordx4 loads each.
// Wave-0 scan per group:
//   phase 0: diag[t] = row t's word g (one LDS read, 64 lanes).
//   phase 1: 64-step serial chain entirely in SGPRs: rw/gm via readfirstlane,
//            row masks via readlane(diag, c) with compile-time c. No LDS in
//            the dependency chain.
//   phase 2: kb update: lanes split rows 0..31/32..63, 32 independent LDS
//            reads each, cndmask by gm, shfl-combine halves.
// Early exit (exact): outputs only consume the first MAXDET kept rows.
#define NMS_THREADS 320
__global__ __launch_bounds__(NMS_THREADS) void k_nms(const uint64_t* __restrict__ keys,
                                                     const float* __restrict__ sboxes,
                                                     const uint64_t* __restrict__ sup,
                                                     int* __restrict__ kidx,
                                                     int* __restrict__ kcount,
                                                     float* __restrict__ out_box,
                                                     float* __restrict__ out_conf) {
    __shared__ uint64_t buf[2][64 * WPR];   // 2 x 16 KB
    __shared__ uint8_t  val[NN];            // 2 KB
    __shared__ uint64_t kmaskS[WPR];
    __shared__ int pfx[WPR];
    __shared__ int s_kc;
    __shared__ int s_done;
    int b = blockIdx.x, t = threadIdx.x;
    const uint64_t* supb = sup + (size_t)b * NN * WPR;
    const uint64_t* keyb = keys + (size_t)b * NN;

    for (int i = t; i < NN; i += NMS_THREADS)
        val[i] = (uint8_t)((uint32_t)(keyb[i] >> 32) > ORD_HALF);  // conf > 0.5f
    if (t < WPR) kmaskS[t] = 0;
    if (t == 0) s_done = 0;
    for (int w = t; w < 64 * WPR / 2; w += NMS_THREADS)   // stage group 0 (16B units)
        ((float4*)buf[0])[w] = ((const float4*)supb)[w];
    __syncthreads();

    int wave = t >> 6;
    uint64_t kb = 0;      // lane l (wave 0, l<32) owns removed-word l
    int cnt = 0;
    if (t < 32) {
        uint64_t vm = 0;
#pragma unroll
        for (int c = 0; c < 64; ++c)
            vm |= ((uint64_t)val[(t << 6) | c]) << c;
        kb = ~vm;         // invalid = pre-removed
    }
    int l2 = t & 31, half = (t >> 5) & 1;

    for (int g = 0; g < WPR; ++g) {
        if (wave > 0) {
            if (g + 1 < WPR) {                      // stage next group: 1024 x 16B
                const float4* src = (const float4*)(supb + (size_t)(g + 1) * 64 * WPR);
                float4* dst = (float4*)buf[(g + 1) & 1];
                int idx = t - 64;                   // 0..255
                float4 r0 = src[idx];
                float4 r1 = src[idx + 256];
                float4 r2 = src[idx + 512];
                float4 r3 = src[idx + 768];
                dst[idx]       = r0;
                dst[idx + 256] = r1;
                dst[idx + 512] = r2;
                dst[idx + 768] = r3;
            }
        } else {
            const uint64_t* bufc = buf[g & 1];
            // phase 0: diag word for row t (all 64 lanes)
            uint64_t diag = bufc[t * WPR + g];
            uint32_t dlo = (uint32_t)diag, dhi = (uint32_t)(diag >> 32);
            // phase 1: serial chain in SGPRs
            uint64_t rwv = __shfl(kb, g);
            uint32_t rw_lo = __builtin_amdgcn_readfirstlane((uint32_t)rwv);
            uint32_t rw_hi = __builtin_amdgcn_readfirstlane((uint32_t)(rwv >> 32));
            uint32_t gm_lo = 0, gm_hi = 0;
#pragma unroll
            for (int c = 0; c < 32; ++c) {
                uint32_t rlo = __builtin_amdgcn_readlane(dlo, c);
                uint32_t rhi = __builtin_amdgcn_readlane(dhi, c);
                if (((rw_lo >> c) & 1u) == 0u) {
                    rw_lo |= rlo; rw_hi |= rhi; gm_lo |= (1u << c);
                }
            }
#pragma unroll
            for (int c = 0; c < 32; ++c) {
                uint32_t rlo = __builtin_amdgcn_readlane(dlo, c + 32);
                uint32_t rhi = __builtin_amdgcn_readlane(dhi, c + 32);
                if (((rw_hi >> c) & 1u) == 0u) {
                    rw_lo |= rlo; rw_hi |= rhi; gm_hi |= (1u << c);
                }
            }
            uint64_t gm = ((uint64_t)gm_hi << 32) | gm_lo;
            // phase 2: kb |= OR over kept rows of this group (independent reads)
            uint32_t gmh = half ? gm_hi : gm_lo;
            const uint64_t* rowp = bufc + ((half << 5) * WPR + l2);
            uint64_t acc = 0;
#pragma unroll
            for (int j = 0; j < 32; ++j) {
                uint64_t row = rowp[(size_t)j * WPR];
                if ((gmh >> j) & 1u) acc |= row;
            }
            acc |= __shfl(acc, t ^ 32);             // combine halves
            if (t < 32) kb |= acc;
            if (t == g) kmaskS[g] = gm;
            cnt += __popcll(gm);                    // uniform in wave 0
            if (cnt >= MAXDET) s_done = 1;
        }
        __syncthreads();                            // staging done + flag visible
        if (s_done) break;
    }

    if (t == 0) {
        int s = 0;
        for (int w2 = 0; w2 < WPR; ++w2) { pfx[w2] = s; s += __popcll(kmaskS[w2]); }
        s_kc = (s < MAXDET) ? s : MAXDET;
        kcount[b] = s_kc;
    }
    __syncthreads();
    for (int i = t; i < NN; i += NMS_THREADS) {
        uint64_t m = kmaskS[i >> 6];
        if ((m >> (i & 63)) & 1ull) {
            int rank = pfx[i >> 6] + __popcll(m & ((1ull << (i & 63)) - 1ull));
            if (rank < MAXDET) {
                ((float4*)out_box)[(size_t)b * MAXDET + rank] =
                    ((const float4*)sboxes)[(size_t)b * NN + i];
                uint64_t kk = keyb[i];
                uint32_t u = (uint32_t)(kk >> 32);
                float cf = (u & 0x80000000u) ? __uint_as_float(u ^ 0x80000000u)
                                             : __uint_as_float(~u);
                out_conf[(size_t)b * MAXDET + rank] = cf;
                kidx[b * MAXDET + rank] = (NN - 1) - (int)(kk & 0xFFFFFFFFull);
            }
        }
    }
    for (int k = s_kc + t; k < MAXDET; k += NMS_THREADS) {
        ((float4*)out_box)[(size_t)b * MAXDET + k] = make_float4(0.f, 0.f, 0.f, 0.f);
        out_conf[(size_t)b * MAXDET + k] = 0.0f;
    }
}

// Kernel 4: softmax gather for kept rows; zero-fill the rest. One wave per slot.
__global__ void k_softmax(const float* __restrict__ cls, const int* __restrict__ kidx,
                          const int* __restrict__ kcount, float* __restrict__ out_cls) {
    int k = blockIdx.x, b = blockIdx.y, lane = threadIdx.x;  // 64 threads
    float* dst = out_cls + ((size_t)b * MAXDET + k) * NC;
    if (k >= kcount[b]) {
        dst[lane] = 0.0f;
        if (lane < NC - 64) dst[64 + lane] = 0.0f;
        return;
    }
    int n = kidx[b * MAXDET + k];
    const float* src = cls + ((size_t)b * NN + n) * NC;
    float x0 = src[lane];
    float x1 = (lane < NC - 64) ? src[64 + lane] : -3.0e38f;
    float m = fmaxf(x0, x1);
    for (int o = 32; o > 0; o >>= 1) m = fmaxf(m, __shfl_xor(m, o));
    float e0 = expf(x0 - m);
    float e1 = (lane < NC - 64) ? expf(x1 - m) : 0.0f;
    float s = e0 + e1;
    for (int o = 32; o > 0; o >>= 1) s += __shfl_xor(s, o);
    dst[lane] = e0 / s;
    if (lane < NC - 64) dst[64 + lane] = e1 / s;
}

extern "C" void kernel_launch(void* const* d_in, const int* in_sizes, int n_in,
                              void* d_out, int out_size, void* d_ws, size_t ws_size,
                              hipStream_t stream) {
    const float* boxes = (const float*)d_in[0];   // [8][2048][4]
    const float* cls   = (const float*)d_in[1];   // [8][2048][80]
    float* out      = (float*)d_out;
    float* out_box  = out;                          // [8][512][4]
    float* out_cls  = out + BB * MAXDET * 4;        // [8][512][80]
    float* out_conf = out + BB * MAXDET * (4 + NC); // [8][512]

    char* ws = (char*)d_ws;
    uint64_t* keysA  = (uint64_t*)(ws + 0);
    uint64_t* keysB  = (uint64_t*)(ws + 131072);
    float*    sboxes = (float*)(ws + 262144);
    int*      kidx   = (int*)(ws + 524288);
    int*      kcount = (int*)(ws + 540672);
    uint64_t* sup    = (uint64_t*)(ws + 544768);

    k_conf<<<(BB * NN) / 256, 256, 0, stream>>>(cls, keysA);
    k_rank<<<dim3(NN / RCHUNK, BB), 512, 0, stream>>>(keysA, keysB, boxes, sboxes);
    k_sup<<<dim3(NN / 64, NN / 256, BB), 256, 0, stream>>>(sboxes, sup);
    k_nms<<<BB, NMS_THREADS, 0, stream>>>(keysB, sboxes, sup, kidx, kcount, out_box, out_conf);
    k_softmax<<<dim3(MAXDET, BB), 64, 0, stream>>>(cls, kidx, kcount, out_cls);
}